// Round 2
// baseline (1618.962 us; speedup 1.0000x reference)
//
#include <hip/hip_runtime.h>
#include <math.h>

#define BB 8
#define SS 1024
#define DD 512
#define HH 8
#define FFF 2048
// M rows total = BB*SS = 8192

__device__ __forceinline__ float gelu_f(float x) {
    return 0.5f * x * (1.0f + erff(x * 0.70710678118654752f));
}

// ---------------- tau embedding: T[bs, 2f]=sin(tau*freq[f]), [2f+1]=cos ----------------
__global__ void tau_embed_kernel(const float* __restrict__ tau,
                                 const float* __restrict__ freq,
                                 float* __restrict__ T) {
    int i = blockIdx.x * blockDim.x + threadIdx.x;   // 0 .. 8192*256-1
    int bs = i >> 8;
    int f  = i & 255;
    float v = tau[bs] * freq[f];
    float s, c;
    sincosf(v, &s, &c);
    *(float2*)&T[(size_t)bs * DD + 2 * f] = make_float2(s, c);
}

// ---------------- generic GEMM: C = act(A @ W^T + bias) [+ res] ----------------
// A: [M,K] row-major, W: [N,K] row-major (torch-style weight), C: [M,N]
// mode: 0 = none, 1 = tanh, 2 = exact gelu
__global__ __launch_bounds__(256) void gemm_nt(
        const float* __restrict__ A, const float* __restrict__ W,
        const float* __restrict__ bias, const float* __restrict__ res,
        float* __restrict__ C, int M, int N, int K, int mode) {
    // tiles transposed in LDS: [k][m] / [k][n], stride 68 (16B-aligned rows, bank-spread)
    __shared__ float As[32 * 68];
    __shared__ float Ws[32 * 68];
    int t  = threadIdx.x;
    int m0 = blockIdx.y << 6;
    int n0 = blockIdx.x << 6;
    int ty = t >> 4, tx = t & 15;
    int r1 = t >> 3;           // 0..31
    int c1 = (t & 7) << 2;     // 0,4,..,28

    float acc[4][4];
#pragma unroll
    for (int i = 0; i < 4; ++i)
#pragma unroll
        for (int j = 0; j < 4; ++j) acc[i][j] = 0.f;

    for (int k0 = 0; k0 < K; k0 += 32) {
        float4 a1 = *(const float4*)&A[(size_t)(m0 + r1) * K + k0 + c1];
        float4 a2 = *(const float4*)&A[(size_t)(m0 + 32 + r1) * K + k0 + c1];
        float4 w1 = *(const float4*)&W[(size_t)(n0 + r1) * K + k0 + c1];
        float4 w2 = *(const float4*)&W[(size_t)(n0 + 32 + r1) * K + k0 + c1];
        __syncthreads();   // protect previous iteration's LDS reads
        As[(c1 + 0) * 68 + r1] = a1.x;  As[(c1 + 1) * 68 + r1] = a1.y;
        As[(c1 + 2) * 68 + r1] = a1.z;  As[(c1 + 3) * 68 + r1] = a1.w;
        As[(c1 + 0) * 68 + 32 + r1] = a2.x;  As[(c1 + 1) * 68 + 32 + r1] = a2.y;
        As[(c1 + 2) * 68 + 32 + r1] = a2.z;  As[(c1 + 3) * 68 + 32 + r1] = a2.w;
        Ws[(c1 + 0) * 68 + r1] = w1.x;  Ws[(c1 + 1) * 68 + r1] = w1.y;
        Ws[(c1 + 2) * 68 + r1] = w1.z;  Ws[(c1 + 3) * 68 + r1] = w1.w;
        Ws[(c1 + 0) * 68 + 32 + r1] = w2.x;  Ws[(c1 + 1) * 68 + 32 + r1] = w2.y;
        Ws[(c1 + 2) * 68 + 32 + r1] = w2.z;  Ws[(c1 + 3) * 68 + 32 + r1] = w2.w;
        __syncthreads();
#pragma unroll
        for (int kk = 0; kk < 32; ++kk) {
            float4 a = *(const float4*)&As[kk * 68 + (ty << 2)];
            float4 b = *(const float4*)&Ws[kk * 68 + (tx << 2)];
            acc[0][0] += a.x * b.x; acc[0][1] += a.x * b.y; acc[0][2] += a.x * b.z; acc[0][3] += a.x * b.w;
            acc[1][0] += a.y * b.x; acc[1][1] += a.y * b.y; acc[1][2] += a.y * b.z; acc[1][3] += a.y * b.w;
            acc[2][0] += a.z * b.x; acc[2][1] += a.z * b.y; acc[2][2] += a.z * b.z; acc[2][3] += a.z * b.w;
            acc[3][0] += a.w * b.x; acc[3][1] += a.w * b.y; acc[3][2] += a.w * b.z; acc[3][3] += a.w * b.w;
        }
    }
#pragma unroll
    for (int i = 0; i < 4; ++i) {
        size_t gm = (size_t)(m0 + (ty << 2) + i);
        int gn = n0 + (tx << 2);
        float4 v;
        v.x = acc[i][0] + bias[gn + 0];
        v.y = acc[i][1] + bias[gn + 1];
        v.z = acc[i][2] + bias[gn + 2];
        v.w = acc[i][3] + bias[gn + 3];
        if (mode == 1) {
            v.x = tanhf(v.x); v.y = tanhf(v.y); v.z = tanhf(v.z); v.w = tanhf(v.w);
        } else if (mode == 2) {
            v.x = gelu_f(v.x); v.y = gelu_f(v.y); v.z = gelu_f(v.z); v.w = gelu_f(v.w);
        }
        if (res) {
            float4 r4 = *(const float4*)&res[gm * N + gn];
            v.x += r4.x; v.y += r4.y; v.z += r4.z; v.w += r4.w;
        }
        *(float4*)&C[gm * N + gn] = v;
    }
}

// ---------------- elementwise gating: base = add + base*(1+g) ----------------
__global__ void gate_combine(float* __restrict__ base, const float* __restrict__ g,
                             const float* __restrict__ add) {
    int i = blockIdx.x * blockDim.x + threadIdx.x;   // per float4
    float4 bs = ((const float4*)base)[i];
    float4 gg = ((const float4*)g)[i];
    float4 ad = ((const float4*)add)[i];
    bs.x = ad.x + bs.x * (1.f + gg.x);
    bs.y = ad.y + bs.y * (1.f + gg.y);
    bs.z = ad.z + bs.z * (1.f + gg.z);
    bs.w = ad.w + bs.w * (1.f + gg.w);
    ((float4*)base)[i] = bs;
}

// ---------------- flash attention with relative |dtau| bias ----------------
// Q,K,V: [B,S,D] with head h occupying cols h*64..h*64+63. O: same layout (ctx).
__global__ __launch_bounds__(256) void attn_kernel(
        const float* __restrict__ Q, const float* __restrict__ K,
        const float* __restrict__ V, const float* __restrict__ tau,
        const float* __restrict__ log_slopes, float* __restrict__ O) {
    __shared__ float Qt[64 * 68];   // [d][row]
    __shared__ float Kt[64 * 68];   // [d][key]
    __shared__ float Vs[64 * 68];   // [key][d]
    __shared__ float Ss[64 * 65];   // [row][key] probs
    int t  = threadIdx.x;
    int bh = blockIdx.y;
    int b  = bh >> 3, h = bh & 7;
    int q0 = blockIdx.x << 6;
    float slope = log1pf(expf(log_slopes[h]));   // softplus, GAMMA=1
    int ty = t >> 4, tx = t & 15;

    // load Q tile, transposed into LDS
#pragma unroll
    for (int j = 0; j < 4; ++j) {
        int idx = (j << 10) + (t << 2);
        int row = idx >> 6, col = idx & 63;
        float4 v = *(const float4*)&Q[((size_t)(b * SS + q0 + row)) * DD + (h << 6) + col];
        Qt[(col + 0) * 68 + row] = v.x;
        Qt[(col + 1) * 68 + row] = v.y;
        Qt[(col + 2) * 68 + row] = v.z;
        Qt[(col + 3) * 68 + row] = v.w;
    }
    float tq[4];
#pragma unroll
    for (int i = 0; i < 4; ++i) tq[i] = tau[b * SS + q0 + (ty << 2) + i];

    float m_r[4], l_r[4], acc[4][4];
#pragma unroll
    for (int i = 0; i < 4; ++i) {
        m_r[i] = -INFINITY; l_r[i] = 0.f;
#pragma unroll
        for (int j = 0; j < 4; ++j) acc[i][j] = 0.f;
    }

    for (int kt = 0; kt < 16; ++kt) {
        int k0 = kt << 6;
        __syncthreads();   // prev PV reads done before overwriting K/V/S tiles
#pragma unroll
        for (int j = 0; j < 4; ++j) {
            int idx = (j << 10) + (t << 2);
            int row = idx >> 6, col = idx & 63;
            float4 kv = *(const float4*)&K[((size_t)(b * SS + k0 + row)) * DD + (h << 6) + col];
            Kt[(col + 0) * 68 + row] = kv.x;
            Kt[(col + 1) * 68 + row] = kv.y;
            Kt[(col + 2) * 68 + row] = kv.z;
            Kt[(col + 3) * 68 + row] = kv.w;
            float4 vv = *(const float4*)&V[((size_t)(b * SS + k0 + row)) * DD + (h << 6) + col];
            *(float4*)&Vs[row * 68 + col] = vv;
        }
        float tk[4];
#pragma unroll
        for (int j = 0; j < 4; ++j) tk[j] = tau[b * SS + k0 + (tx << 2) + j];
        __syncthreads();

        // scores: 4x4 per thread over 64 dims
        float s[4][4];
#pragma unroll
        for (int i = 0; i < 4; ++i)
#pragma unroll
            for (int j = 0; j < 4; ++j) s[i][j] = 0.f;
#pragma unroll
        for (int d = 0; d < 64; ++d) {
            float4 a  = *(const float4*)&Qt[d * 68 + (ty << 2)];
            float4 bb = *(const float4*)&Kt[d * 68 + (tx << 2)];
            s[0][0] += a.x * bb.x; s[0][1] += a.x * bb.y; s[0][2] += a.x * bb.z; s[0][3] += a.x * bb.w;
            s[1][0] += a.y * bb.x; s[1][1] += a.y * bb.y; s[1][2] += a.y * bb.z; s[1][3] += a.y * bb.w;
            s[2][0] += a.z * bb.x; s[2][1] += a.z * bb.y; s[2][2] += a.z * bb.z; s[2][3] += a.z * bb.w;
            s[3][0] += a.w * bb.x; s[3][1] += a.w * bb.y; s[3][2] += a.w * bb.z; s[3][3] += a.w * bb.w;
        }
#pragma unroll
        for (int i = 0; i < 4; ++i)
#pragma unroll
            for (int j = 0; j < 4; ++j)
                s[i][j] = s[i][j] * 0.125f - slope * fabsf(tq[i] - tk[j]);

        // online softmax (row stats replicated across the 16-lane tx group)
#pragma unroll
        for (int i = 0; i < 4; ++i) {
            float mt = fmaxf(fmaxf(s[i][0], s[i][1]), fmaxf(s[i][2], s[i][3]));
            mt = fmaxf(mt, __shfl_xor(mt, 1));
            mt = fmaxf(mt, __shfl_xor(mt, 2));
            mt = fmaxf(mt, __shfl_xor(mt, 4));
            mt = fmaxf(mt, __shfl_xor(mt, 8));
            float mn  = fmaxf(m_r[i], mt);
            float fac = expf(m_r[i] - mn);
            float rs = 0.f;
#pragma unroll
            for (int j = 0; j < 4; ++j) {
                float p = expf(s[i][j] - mn);
                s[i][j] = p;
                rs += p;
            }
            rs += __shfl_xor(rs, 1);
            rs += __shfl_xor(rs, 2);
            rs += __shfl_xor(rs, 4);
            rs += __shfl_xor(rs, 8);
            l_r[i] = l_r[i] * fac + rs;
            m_r[i] = mn;
#pragma unroll
            for (int j = 0; j < 4; ++j) acc[i][j] *= fac;
#pragma unroll
            for (int j = 0; j < 4; ++j) Ss[((ty << 2) + i) * 65 + (tx << 2) + j] = s[i][j];
        }
        __syncthreads();

        // PV: acc[i][j] += sum_k P[r_i][k] * V[k][c_j]
#pragma unroll
        for (int k = 0; k < 64; ++k) {
            float4 v4 = *(const float4*)&Vs[k * 68 + (tx << 2)];
            float p0 = Ss[((ty << 2) + 0) * 65 + k];
            float p1 = Ss[((ty << 2) + 1) * 65 + k];
            float p2 = Ss[((ty << 2) + 2) * 65 + k];
            float p3 = Ss[((ty << 2) + 3) * 65 + k];
            acc[0][0] += p0 * v4.x; acc[0][1] += p0 * v4.y; acc[0][2] += p0 * v4.z; acc[0][3] += p0 * v4.w;
            acc[1][0] += p1 * v4.x; acc[1][1] += p1 * v4.y; acc[1][2] += p1 * v4.z; acc[1][3] += p1 * v4.w;
            acc[2][0] += p2 * v4.x; acc[2][1] += p2 * v4.y; acc[2][2] += p2 * v4.z; acc[2][3] += p2 * v4.w;
            acc[3][0] += p3 * v4.x; acc[3][1] += p3 * v4.y; acc[3][2] += p3 * v4.z; acc[3][3] += p3 * v4.w;
        }
    }
#pragma unroll
    for (int i = 0; i < 4; ++i) {
        float inv = 1.0f / l_r[i];
        float4 v;
        v.x = acc[i][0] * inv; v.y = acc[i][1] * inv;
        v.z = acc[i][2] * inv; v.w = acc[i][3] * inv;
        *(float4*)&O[((size_t)(b * SS + q0 + (ty << 2) + i)) * DD + (h << 6) + (tx << 2)] = v;
    }
}

// ---------------- layernorm over rows of 512 ----------------
__global__ __launch_bounds__(64) void ln_kernel(const float* __restrict__ X,
                                                const float* __restrict__ g,
                                                const float* __restrict__ b,
                                                float* __restrict__ out) {
    int row = blockIdx.x;
    int t = threadIdx.x;
    const float* xr = X + (size_t)row * DD;
    float4 v0 = *(const float4*)&xr[t * 4];
    float4 v1 = *(const float4*)&xr[256 + t * 4];
    float s  = v0.x + v0.y + v0.z + v0.w + v1.x + v1.y + v1.z + v1.w;
    float sq = v0.x * v0.x + v0.y * v0.y + v0.z * v0.z + v0.w * v0.w
             + v1.x * v1.x + v1.y * v1.y + v1.z * v1.z + v1.w * v1.w;
#pragma unroll
    for (int off = 1; off < 64; off <<= 1) {
        s  += __shfl_xor(s, off);
        sq += __shfl_xor(sq, off);
    }
    float mean = s * (1.0f / 512.0f);
    float var  = sq * (1.0f / 512.0f) - mean * mean;
    float rstd = rsqrtf(var + 1e-5f);
    float* orow = out + (size_t)row * DD;
    int c0 = t * 4, c1 = 256 + t * 4;
    float4 o0, o1;
    o0.x = (v0.x - mean) * rstd * g[c0 + 0] + b[c0 + 0];
    o0.y = (v0.y - mean) * rstd * g[c0 + 1] + b[c0 + 1];
    o0.z = (v0.z - mean) * rstd * g[c0 + 2] + b[c0 + 2];
    o0.w = (v0.w - mean) * rstd * g[c0 + 3] + b[c0 + 3];
    o1.x = (v1.x - mean) * rstd * g[c1 + 0] + b[c1 + 0];
    o1.y = (v1.y - mean) * rstd * g[c1 + 1] + b[c1 + 1];
    o1.z = (v1.z - mean) * rstd * g[c1 + 2] + b[c1 + 2];
    o1.w = (v1.w - mean) * rstd * g[c1 + 3] + b[c1 + 3];
    *(float4*)&orow[c0] = o0;
    *(float4*)&orow[c1] = o1;
}

extern "C" void kernel_launch(void* const* d_in, const int* in_sizes, int n_in,
                              void* d_out, int out_size, void* d_ws, size_t ws_size,
                              hipStream_t stream) {
    (void)in_sizes; (void)n_in; (void)out_size; (void)ws_size;
    const float* src        = (const float*)d_in[0];
    const float* tau        = (const float*)d_in[1];
    const float* Wq  = (const float*)d_in[2];  const float* bq  = (const float*)d_in[3];
    const float* Wk  = (const float*)d_in[4];  const float* bk  = (const float*)d_in[5];
    const float* Wv  = (const float*)d_in[6];  const float* bv  = (const float*)d_in[7];
    const float* Wo  = (const float*)d_in[8];  const float* bo  = (const float*)d_in[9];
    const float* Wqg = (const float*)d_in[10]; const float* bqg = (const float*)d_in[11];
    const float* Wqb = (const float*)d_in[12]; const float* bqb = (const float*)d_in[13];
    const float* Wkg = (const float*)d_in[14]; const float* bkg = (const float*)d_in[15];
    const float* Wkb = (const float*)d_in[16]; const float* bkb = (const float*)d_in[17];
    const float* log_slopes = (const float*)d_in[18];
    const float* W1  = (const float*)d_in[19]; const float* b1  = (const float*)d_in[20];
    const float* W2  = (const float*)d_in[21]; const float* b2  = (const float*)d_in[22];
    const float* ln1_g = (const float*)d_in[23]; const float* ln1_b = (const float*)d_in[24];
    const float* ln2_g = (const float*)d_in[25]; const float* ln2_b = (const float*)d_in[26];
    const float* tau_freq = (const float*)d_in[27];
    float* out = (float*)d_out;

    // Workspace plan (96 MB peak, liveness-aliased):
    //   [ 0,16) T (tau embed) -> Ctx (attn out) -> Y (ffn out)
    //   [16,32) G (tanh gate) -> X (post-LN1)
    //   [32,48) Bb (gate bias)   \
    //   [48,64) Qb (q)            \  all dead after attention:
    //   [64,80) Kb (k)            /  [32,96) reused as H1 [8192x2048]
    //   [80,96) Vb (v)           /
    char* ws = (char*)d_ws;
    const size_t MB = 1ull << 20;
    float* T   = (float*)(ws + 0 * MB);
    float* G   = (float*)(ws + 16 * MB);
    float* Bb  = (float*)(ws + 32 * MB);
    float* Qb  = (float*)(ws + 48 * MB);
    float* Kb  = (float*)(ws + 64 * MB);
    float* Vb  = (float*)(ws + 80 * MB);
    float* Ctx = T;
    float* X   = G;
    float* H1  = Bb;                      // [32,96) MB
    float* Y   = T;

    const int M = BB * SS;                 // 8192
    dim3 blk(256);
    dim3 gD(DD / 64, M / 64);              // 8 x 128
    dim3 gF(FFF / 64, M / 64);             // 32 x 128

    tau_embed_kernel<<<(M * 256) / 256, 256, 0, stream>>>(tau, tau_freq, T);

    // Q = src@Wq^T+bq ; gated by tau-embed
    gemm_nt<<<gD, blk, 0, stream>>>(src, Wq, bq, nullptr, Qb, M, DD, DD, 0);
    gemm_nt<<<gD, blk, 0, stream>>>(T, Wqg, bqg, nullptr, G, M, DD, DD, 1);
    gemm_nt<<<gD, blk, 0, stream>>>(T, Wqb, bqb, nullptr, Bb, M, DD, DD, 0);
    gate_combine<<<(M * DD / 4) / 256, 256, 0, stream>>>(Qb, G, Bb);

    // K
    gemm_nt<<<gD, blk, 0, stream>>>(src, Wk, bk, nullptr, Kb, M, DD, DD, 0);
    gemm_nt<<<gD, blk, 0, stream>>>(T, Wkg, bkg, nullptr, G, M, DD, DD, 1);
    gemm_nt<<<gD, blk, 0, stream>>>(T, Wkb, bkb, nullptr, Bb, M, DD, DD, 0);
    gate_combine<<<(M * DD / 4) / 256, 256, 0, stream>>>(Kb, G, Bb);

    // V
    gemm_nt<<<gD, blk, 0, stream>>>(src, Wv, bv, nullptr, Vb, M, DD, DD, 0);

    // attention -> Ctx (in [B,S,D] head-concat layout)
    attn_kernel<<<dim3(SS / 64, BB * HH), blk, 0, stream>>>(Qb, Kb, Vb, tau, log_slopes, Ctx);

    // X = Ctx@Wo^T + bo + src ; LN1 in place
    gemm_nt<<<gD, blk, 0, stream>>>(Ctx, Wo, bo, src, X, M, DD, DD, 0);
    ln_kernel<<<M, 64, 0, stream>>>(X, ln1_g, ln1_b, X);

    // FFN (H1 overlays the dead Bb/Qb/Kb/Vb region)
    gemm_nt<<<gF, blk, 0, stream>>>(X, W1, b1, nullptr, H1, M, FFF, DD, 2);
    gemm_nt<<<gD, blk, 0, stream>>>(H1, W2, b2, X, Y, M, DD, FFF, 0);

    // LN2 -> out
    ln_kernel<<<M, 64, 0, stream>>>(Y, ln2_g, ln2_b, out);
}

// Round 14
// 915.654 us; speedup vs baseline: 1.7681x; 1.7681x over previous
//
#include <hip/hip_runtime.h>
#include <math.h>

#define BB 8
#define SS 1024
#define DD 512
#define HH 8
#define FFF 2048
// M rows total = BB*SS = 8192

typedef unsigned short ushortT;
typedef __attribute__((ext_vector_type(8))) short bf16x8;
typedef __attribute__((ext_vector_type(4))) float f32x4;

__device__ __forceinline__ float gelu_f(float x) {
    return 0.5f * x * (1.0f + erff(x * 0.70710678118654752f));
}

// round-to-nearest-even fp32 -> bf16 (finite inputs)
__device__ __forceinline__ ushortT f2bf(float f) {
    unsigned int u = __float_as_uint(f);
    return (ushortT)((u + 0x7fffu + ((u >> 16) & 1u)) >> 16);
}

__device__ __forceinline__ void gload_lds16(const void* g, void* l) {
    __builtin_amdgcn_global_load_lds(
        (const __attribute__((address_space(1))) void*)g,
        (__attribute__((address_space(3))) void*)l, 16, 0, 0);
}

// ---------------- fp32 -> bf16 cast (vectorized) ----------------
__global__ __launch_bounds__(256) void cast_bf16_kernel(const float* __restrict__ in,
                                                        ushortT* __restrict__ out) {
    int i = blockIdx.x * blockDim.x + threadIdx.x;   // per float4
    float4 v = ((const float4*)in)[i];
    ushort4 o;
    o.x = f2bf(v.x); o.y = f2bf(v.y); o.z = f2bf(v.z); o.w = f2bf(v.w);
    ((ushort4*)out)[i] = o;
}

// ---------------- tau embedding, bf16 out: T[bs,2f]=sin, [2f+1]=cos ----------------
__global__ __launch_bounds__(256) void tau_embed_kernel(const float* __restrict__ tau,
                                                        const float* __restrict__ freq,
                                                        ushortT* __restrict__ T) {
    int i = blockIdx.x * blockDim.x + threadIdx.x;   // 0 .. 8192*256-1
    int bs = i >> 8;
    int f  = i & 255;
    float v = tau[bs] * freq[f];
    float s, c;
    sincosf(v, &s, &c);
    ushort2 p;
    p.x = f2bf(s); p.y = f2bf(c);
    *(ushort2*)&T[(size_t)bs * DD + 2 * f] = p;
}

// ---------------- bf16 MFMA GEMM (m97 structure): C = act(A @ W^T + bias) [+res] ----
// A: [M,K] bf16 row-major, W: [N,K] bf16 row-major. Tile 128x128, BK=32, 4 waves.
// mode: 0 none, 1 tanh, 2 gelu. Cb!=null -> bf16 out, else fp32 to Cf.
__global__ __launch_bounds__(256) void gemm_bt_mfma(
        const ushortT* __restrict__ A, const ushortT* __restrict__ W,
        const float* __restrict__ bias, const float* __restrict__ res,
        float* __restrict__ Cf, ushortT* __restrict__ Cb,
        int M, int N, int K, int mode) {
    __shared__ ushortT As[128 * 32];    // 8 KB, row-major [128][32], 64 B rows
    __shared__ ushortT Bs[128 * 32];
    int t    = threadIdx.x;
    int lane = t & 63;
    int w    = t >> 6;                  // wave 0..3
    int wr   = w >> 1, wc = w & 1;      // 2x2 wave grid, 64x64 per wave
    int m0 = blockIdx.y << 7;
    int n0 = blockIdx.x << 7;

    f32x4 acc[4][4];
#pragma unroll
    for (int i = 0; i < 4; ++i)
#pragma unroll
        for (int j = 0; j < 4; ++j) acc[i][j] = (f32x4){0.f, 0.f, 0.f, 0.f};

    // staging geometry: byte b of tile -> row b/64, bf16-col (b%64)/2
    int srow = lane >> 2;               // + 16*(i*4+w)
    int scol = (lane & 3) << 3;         // k offset in elements

    for (int k0 = 0; k0 < K; k0 += 32) {
#pragma unroll
        for (int i = 0; i < 2; ++i) {
            int off  = (i * 4 + w) << 10;          // uniform per wave
            int row  = (i * 64 + w * 16) + srow;
            gload_lds16(&A[(size_t)(m0 + row) * K + k0 + scol], (char*)As + off);
            gload_lds16(&W[(size_t)(n0 + row) * K + k0 + scol], (char*)Bs + off);
        }
        __syncthreads();   // drains vmcnt -> LDS tiles ready

        bf16x8 af[4], bf[4];
#pragma unroll
        for (int i = 0; i < 4; ++i) {
            af[i] = *(const bf16x8*)&As[(wr * 64 + i * 16 + (lane & 15)) * 32 + ((lane >> 4) << 3)];
            bf[i] = *(const bf16x8*)&Bs[(wc * 64 + i * 16 + (lane & 15)) * 32 + ((lane >> 4) << 3)];
        }
#pragma unroll
        for (int mi = 0; mi < 4; ++mi)
#pragma unroll
            for (int ni = 0; ni < 4; ++ni)
                acc[mi][ni] = __builtin_amdgcn_mfma_f32_16x16x32_bf16(
                    af[mi], bf[ni], acc[mi][ni], 0, 0, 0);
        __syncthreads();   // all reads done before next stage overwrites
    }

    // epilogue: C/D layout row=(lane>>4)*4+reg, col=lane&15 [m89/m91]
    int cbase = n0 + wc * 64 + (lane & 15);
    float bcol[4];
#pragma unroll
    for (int ni = 0; ni < 4; ++ni) bcol[ni] = bias[cbase + ni * 16];
    int rbase = m0 + wr * 64 + ((lane >> 4) << 2);
#pragma unroll
    for (int mi = 0; mi < 4; ++mi) {
#pragma unroll
        for (int r = 0; r < 4; ++r) {
            size_t grow = (size_t)(rbase + mi * 16 + r);
#pragma unroll
            for (int ni = 0; ni < 4; ++ni) {
                int col = cbase + ni * 16;
                float v = acc[mi][ni][r] + bcol[ni];
                if (mode == 1)      v = tanhf(v);
                else if (mode == 2) v = gelu_f(v);
                if (res) v += res[grow * N + col];
                if (Cb)  Cb[grow * N + col] = f2bf(v);
                else     Cf[grow * N + col] = v;
            }
        }
    }
}

// ---------------- elementwise gating: base = add + base*(1+g) ----------------
__global__ void gate_combine(float* __restrict__ base, const float* __restrict__ g,
                             const float* __restrict__ add) {
    int i = blockIdx.x * blockDim.x + threadIdx.x;   // per float4
    float4 bs = ((const float4*)base)[i];
    float4 gg = ((const float4*)g)[i];
    float4 ad = ((const float4*)add)[i];
    bs.x = ad.x + bs.x * (1.f + gg.x);
    bs.y = ad.y + bs.y * (1.f + gg.y);
    bs.z = ad.z + bs.z * (1.f + gg.z);
    bs.w = ad.w + bs.w * (1.f + gg.w);
    ((float4*)base)[i] = bs;
}

// ---------------- flash attention (fp32) with relative |dtau| bias ----------------
// Q,K,V: [B,S,D] head h in cols h*64..h*64+63. O may alias Q (block owns its slice).
__global__ __launch_bounds__(256) void attn_kernel(
        const float* __restrict__ Q, const float* __restrict__ K,
        const float* __restrict__ V, const float* __restrict__ tau,
        const float* __restrict__ log_slopes, float* __restrict__ O) {
    __shared__ float Qt[64 * 68];   // [d][row]
    __shared__ float Kt[64 * 68];   // [d][key]
    __shared__ float Vs[64 * 68];   // [key][d]
    __shared__ float Ss[64 * 65];   // [row][key] probs
    int t  = threadIdx.x;
    int bh = blockIdx.y;
    int b  = bh >> 3, h = bh & 7;
    int q0 = blockIdx.x << 6;
    float slope = log1pf(expf(log_slopes[h]));   // softplus, GAMMA=1
    int ty = t >> 4, tx = t & 15;

#pragma unroll
    for (int j = 0; j < 4; ++j) {
        int idx = (j << 10) + (t << 2);
        int row = idx >> 6, col = idx & 63;
        float4 v = *(const float4*)&Q[((size_t)(b * SS + q0 + row)) * DD + (h << 6) + col];
        Qt[(col + 0) * 68 + row] = v.x;
        Qt[(col + 1) * 68 + row] = v.y;
        Qt[(col + 2) * 68 + row] = v.z;
        Qt[(col + 3) * 68 + row] = v.w;
    }
    float tq[4];
#pragma unroll
    for (int i = 0; i < 4; ++i) tq[i] = tau[b * SS + q0 + (ty << 2) + i];

    float m_r[4], l_r[4], acc[4][4];
#pragma unroll
    for (int i = 0; i < 4; ++i) {
        m_r[i] = -INFINITY; l_r[i] = 0.f;
#pragma unroll
        for (int j = 0; j < 4; ++j) acc[i][j] = 0.f;
    }

    for (int kt = 0; kt < 16; ++kt) {
        int k0 = kt << 6;
        __syncthreads();
#pragma unroll
        for (int j = 0; j < 4; ++j) {
            int idx = (j << 10) + (t << 2);
            int row = idx >> 6, col = idx & 63;
            float4 kv = *(const float4*)&K[((size_t)(b * SS + k0 + row)) * DD + (h << 6) + col];
            Kt[(col + 0) * 68 + row] = kv.x;
            Kt[(col + 1) * 68 + row] = kv.y;
            Kt[(col + 2) * 68 + row] = kv.z;
            Kt[(col + 3) * 68 + row] = kv.w;
            float4 vv = *(const float4*)&V[((size_t)(b * SS + k0 + row)) * DD + (h << 6) + col];
            *(float4*)&Vs[row * 68 + col] = vv;
        }
        float tk[4];
#pragma unroll
        for (int j = 0; j < 4; ++j) tk[j] = tau[b * SS + k0 + (tx << 2) + j];
        __syncthreads();

        float s[4][4];
#pragma unroll
        for (int i = 0; i < 4; ++i)
#pragma unroll
            for (int j = 0; j < 4; ++j) s[i][j] = 0.f;
#pragma unroll
        for (int d = 0; d < 64; ++d) {
            float4 a  = *(const float4*)&Qt[d * 68 + (ty << 2)];
            float4 bb = *(const float4*)&Kt[d * 68 + (tx << 2)];
            s[0][0] += a.x * bb.x; s[0][1] += a.x * bb.y; s[0][2] += a.x * bb.z; s[0][3] += a.x * bb.w;
            s[1][0] += a.y * bb.x; s[1][1] += a.y * bb.y; s[1][2] += a.y * bb.z; s[1][3] += a.y * bb.w;
            s[2][0] += a.z * bb.x; s[2][1] += a.z * bb.y; s[2][2] += a.z * bb.z; s[2][3] += a.z * bb.w;
            s[3][0] += a.w * bb.x; s[3][1] += a.w * bb.y; s[3][2] += a.w * bb.z; s[3][3] += a.w * bb.w;
        }
#pragma unroll
        for (int i = 0; i < 4; ++i)
#pragma unroll
            for (int j = 0; j < 4; ++j)
                s[i][j] = s[i][j] * 0.125f - slope * fabsf(tq[i] - tk[j]);

#pragma unroll
        for (int i = 0; i < 4; ++i) {
            float mt = fmaxf(fmaxf(s[i][0], s[i][1]), fmaxf(s[i][2], s[i][3]));
            mt = fmaxf(mt, __shfl_xor(mt, 1));
            mt = fmaxf(mt, __shfl_xor(mt, 2));
            mt = fmaxf(mt, __shfl_xor(mt, 4));
            mt = fmaxf(mt, __shfl_xor(mt, 8));
            float mn  = fmaxf(m_r[i], mt);
            float fac = expf(m_r[i] - mn);
            float rs = 0.f;
#pragma unroll
            for (int j = 0; j < 4; ++j) {
                float p = expf(s[i][j] - mn);
                s[i][j] = p;
                rs += p;
            }
            rs += __shfl_xor(rs, 1);
            rs += __shfl_xor(rs, 2);
            rs += __shfl_xor(rs, 4);
            rs += __shfl_xor(rs, 8);
            l_r[i] = l_r[i] * fac + rs;
            m_r[i] = mn;
#pragma unroll
            for (int j = 0; j < 4; ++j) acc[i][j] *= fac;
#pragma unroll
            for (int j = 0; j < 4; ++j) Ss[((ty << 2) + i) * 65 + (tx << 2) + j] = s[i][j];
        }
        __syncthreads();

#pragma unroll
        for (int k = 0; k < 64; ++k) {
            float4 v4 = *(const float4*)&Vs[k * 68 + (tx << 2)];
            float p0 = Ss[((ty << 2) + 0) * 65 + k];
            float p1 = Ss[((ty << 2) + 1) * 65 + k];
            float p2 = Ss[((ty << 2) + 2) * 65 + k];
            float p3 = Ss[((ty << 2) + 3) * 65 + k];
            acc[0][0] += p0 * v4.x; acc[0][1] += p0 * v4.y; acc[0][2] += p0 * v4.z; acc[0][3] += p0 * v4.w;
            acc[1][0] += p1 * v4.x; acc[1][1] += p1 * v4.y; acc[1][2] += p1 * v4.z; acc[1][3] += p1 * v4.w;
            acc[2][0] += p2 * v4.x; acc[2][1] += p2 * v4.y; acc[2][2] += p2 * v4.z; acc[2][3] += p2 * v4.w;
            acc[3][0] += p3 * v4.x; acc[3][1] += p3 * v4.y; acc[3][2] += p3 * v4.z; acc[3][3] += p3 * v4.w;
        }
    }
#pragma unroll
    for (int i = 0; i < 4; ++i) {
        float inv = 1.0f / l_r[i];
        float4 v;
        v.x = acc[i][0] * inv; v.y = acc[i][1] * inv;
        v.z = acc[i][2] * inv; v.w = acc[i][3] * inv;
        *(float4*)&O[((size_t)(b * SS + q0 + (ty << 2) + i)) * DD + (h << 6) + (tx << 2)] = v;
    }
}

// ---------------- layernorm over rows of 512 (fp32 out + optional bf16 out) --------
__global__ __launch_bounds__(64) void ln_kernel(const float* __restrict__ X,
                                                const float* __restrict__ g,
                                                const float* __restrict__ b,
                                                float* __restrict__ out,
                                                ushortT* __restrict__ outb) {
    int row = blockIdx.x;
    int t = threadIdx.x;
    const float* xr = X + (size_t)row * DD;
    float4 v0 = *(const float4*)&xr[t * 4];
    float4 v1 = *(const float4*)&xr[256 + t * 4];
    float s  = v0.x + v0.y + v0.z + v0.w + v1.x + v1.y + v1.z + v1.w;
    float sq = v0.x * v0.x + v0.y * v0.y + v0.z * v0.z + v0.w * v0.w
             + v1.x * v1.x + v1.y * v1.y + v1.z * v1.z + v1.w * v1.w;
#pragma unroll
    for (int off = 1; off < 64; off <<= 1) {
        s  += __shfl_xor(s, off);
        sq += __shfl_xor(sq, off);
    }
    float mean = s * (1.0f / 512.0f);
    float var  = sq * (1.0f / 512.0f) - mean * mean;
    float rstd = rsqrtf(var + 1e-5f);
    int c0 = t * 4, c1 = 256 + t * 4;
    float4 o0, o1;
    o0.x = (v0.x - mean) * rstd * g[c0 + 0] + b[c0 + 0];
    o0.y = (v0.y - mean) * rstd * g[c0 + 1] + b[c0 + 1];
    o0.z = (v0.z - mean) * rstd * g[c0 + 2] + b[c0 + 2];
    o0.w = (v0.w - mean) * rstd * g[c0 + 3] + b[c0 + 3];
    o1.x = (v1.x - mean) * rstd * g[c1 + 0] + b[c1 + 0];
    o1.y = (v1.y - mean) * rstd * g[c1 + 1] + b[c1 + 1];
    o1.z = (v1.z - mean) * rstd * g[c1 + 2] + b[c1 + 2];
    o1.w = (v1.w - mean) * rstd * g[c1 + 3] + b[c1 + 3];
    float* orow = out + (size_t)row * DD;
    *(float4*)&orow[c0] = o0;
    *(float4*)&orow[c1] = o1;
    if (outb) {
        ushort4 h0, h1;
        h0.x = f2bf(o0.x); h0.y = f2bf(o0.y); h0.z = f2bf(o0.z); h0.w = f2bf(o0.w);
        h1.x = f2bf(o1.x); h1.y = f2bf(o1.y); h1.z = f2bf(o1.z); h1.w = f2bf(o1.w);
        ushortT* brow = outb + (size_t)row * DD;
        *(ushort4*)&brow[c0] = h0;
        *(ushort4*)&brow[c1] = h1;
    }
}

extern "C" void kernel_launch(void* const* d_in, const int* in_sizes, int n_in,
                              void* d_out, int out_size, void* d_ws, size_t ws_size,
                              hipStream_t stream) {
    (void)in_sizes; (void)n_in; (void)out_size; (void)ws_size;
    const float* src        = (const float*)d_in[0];
    const float* tau        = (const float*)d_in[1];
    const float* Wq  = (const float*)d_in[2];  const float* bq  = (const float*)d_in[3];
    const float* Wk  = (const float*)d_in[4];  const float* bk  = (const float*)d_in[5];
    const float* Wv  = (const float*)d_in[6];  const float* bv  = (const float*)d_in[7];
    const float* Wo  = (const float*)d_in[8];  const float* bo  = (const float*)d_in[9];
    const float* Wqg = (const float*)d_in[10]; const float* bqg = (const float*)d_in[11];
    const float* Wqb = (const float*)d_in[12]; const float* bqb = (const float*)d_in[13];
    const float* Wkg = (const float*)d_in[14]; const float* bkg = (const float*)d_in[15];
    const float* Wkb = (const float*)d_in[16]; const float* bkb = (const float*)d_in[17];
    const float* log_slopes = (const float*)d_in[18];
    const float* W1  = (const float*)d_in[19]; const float* b1  = (const float*)d_in[20];
    const float* W2  = (const float*)d_in[21]; const float* b2  = (const float*)d_in[22];
    const float* ln1_g = (const float*)d_in[23]; const float* ln1_b = (const float*)d_in[24];
    const float* ln2_g = (const float*)d_in[25]; const float* ln2_b = (const float*)d_in[26];
    const float* tau_freq = (const float*)d_in[27];
    float* out = (float*)d_out;

    // Workspace (peak 88 MB, liveness-aliased):
    //  [ 0, 8)  T_bf        -> Ctx_bf
    //  [ 8,16)  src_bf      -> X_bf
    //  [16,24)  weights bf16 (8x0.5MB @16, W1 @20, W2 @22)
    //  [24,40)  Q f32 -> Ctx f32 (attn in-place) -> Y f32
    //  [40,56)  K f32 -> X f32
    //  [56,72)  G f32 -> V f32 -> H1 lo
    //  [72,88)  Bb f32 -> H1 hi
    char* ws = (char*)d_ws;
    const size_t MB = 1ull << 20;
    ushortT* T_bf   = (ushortT*)(ws + 0 * MB);
    ushortT* src_bf = (ushortT*)(ws + 8 * MB);
    ushortT* Wq_bf  = (ushortT*)(ws + 16 * MB);
    ushortT* Wk_bf  = (ushortT*)(ws + 16 * MB + 512 * 1024);
    ushortT* Wv_bf  = (ushortT*)(ws + 17 * MB);
    ushortT* Wo_bf  = (ushortT*)(ws + 17 * MB + 512 * 1024);
    ushortT* Wqg_bf = (ushortT*)(ws + 18 * MB);
    ushortT* Wqb_bf = (ushortT*)(ws + 18 * MB + 512 * 1024);
    ushortT* Wkg_bf = (ushortT*)(ws + 19 * MB);
    ushortT* Wkb_bf = (ushortT*)(ws + 19 * MB + 512 * 1024);
    ushortT* W1_bf  = (ushortT*)(ws + 20 * MB);
    ushortT* W2_bf  = (ushortT*)(ws + 22 * MB);
    float*   Qf     = (float*)(ws + 24 * MB);
    float*   Kf     = (float*)(ws + 40 * MB);
    float*   Gf     = (float*)(ws + 56 * MB);
    float*   Bbf    = (float*)(ws + 72 * MB);
    float*   Vf     = Gf;                       // after gates done
    float*   Ctx    = Qf;                       // attn in-place
    ushortT* Ctx_bf = T_bf;
    float*   Xf     = Kf;
    ushortT* X_bf   = src_bf;
    ushortT* H1_bf  = (ushortT*)(ws + 56 * MB); // 32 MB
    float*   Yf     = Qf;

    const int M = BB * SS;                 // 8192
    dim3 blk(256);

    // --- casts (weights + src) ---
    cast_bf16_kernel<<<256,  blk, 0, stream>>>(Wq,  Wq_bf);
    cast_bf16_kernel<<<256,  blk, 0, stream>>>(Wk,  Wk_bf);
    cast_bf16_kernel<<<256,  blk, 0, stream>>>(Wv,  Wv_bf);
    cast_bf16_kernel<<<256,  blk, 0, stream>>>(Wo,  Wo_bf);
    cast_bf16_kernel<<<256,  blk, 0, stream>>>(Wqg, Wqg_bf);
    cast_bf16_kernel<<<256,  blk, 0, stream>>>(Wqb, Wqb_bf);
    cast_bf16_kernel<<<256,  blk, 0, stream>>>(Wkg, Wkg_bf);
    cast_bf16_kernel<<<256,  blk, 0, stream>>>(Wkb, Wkb_bf);
    cast_bf16_kernel<<<1024, blk, 0, stream>>>(W1,  W1_bf);
    cast_bf16_kernel<<<1024, blk, 0, stream>>>(W2,  W2_bf);
    cast_bf16_kernel<<<4096, blk, 0, stream>>>(src, src_bf);
    tau_embed_kernel<<<M, blk, 0, stream>>>(tau, tau_freq, T_bf);

    auto gemm = [&](const ushortT* A, const ushortT* Wb, const float* bias,
                    const float* res, float* Cf, ushortT* Cb, int N, int K, int mode) {
        dim3 g(N / 128, M / 128);
        gemm_bt_mfma<<<g, blk, 0, stream>>>(A, Wb, bias, res, Cf, Cb, M, N, K, mode);
    };

    // Q
    gemm(src_bf, Wq_bf,  bq,  nullptr, Qf,  nullptr, DD, DD, 0);
    gemm(T_bf,   Wqg_bf, bqg, nullptr, Gf,  nullptr, DD, DD, 1);
    gemm(T_bf,   Wqb_bf, bqb, nullptr, Bbf, nullptr, DD, DD, 0);
    gate_combine<<<(M * DD / 4) / 256, blk, 0, stream>>>(Qf, Gf, Bbf);
    // K
    gemm(src_bf, Wk_bf,  bk,  nullptr, Kf,  nullptr, DD, DD, 0);
    gemm(T_bf,   Wkg_bf, bkg, nullptr, Gf,  nullptr, DD, DD, 1);
    gemm(T_bf,   Wkb_bf, bkb, nullptr, Bbf, nullptr, DD, DD, 0);
    gate_combine<<<(M * DD / 4) / 256, blk, 0, stream>>>(Kf, Gf, Bbf);
    // V (overwrites gate buffer after gates are consumed)
    gemm(src_bf, Wv_bf, bv, nullptr, Vf, nullptr, DD, DD, 0);

    // attention (fp32), O aliases Q
    attn_kernel<<<dim3(SS / 64, BB * HH), blk, 0, stream>>>(Qf, Kf, Vf, tau, log_slopes, Ctx);

    // X = Ctx@Wo^T + bo + src ; LN1 -> X (f32) + X_bf
    cast_bf16_kernel<<<4096, blk, 0, stream>>>(Ctx, Ctx_bf);
    gemm(Ctx_bf, Wo_bf, bo, src, Xf, nullptr, DD, DD, 0);
    ln_kernel<<<M, 64, 0, stream>>>(Xf, ln1_g, ln1_b, Xf, X_bf);

    // FFN: H1 = gelu(X@W1^T+b1) in bf16 ; Y = H1@W2^T + b2 + X
    gemm(X_bf, W1_bf, b1, nullptr, nullptr, H1_bf, FFF, DD, 2);
    gemm(H1_bf, W2_bf, b2, Xf, Yf, nullptr, DD, FFF, 0);

    // LN2 -> out
    ln_kernel<<<M, 64, 0, stream>>>(Yf, ln2_g, ln2_b, out, nullptr);
}

// Round 15
// 576.515 us; speedup vs baseline: 2.8082x; 1.5883x over previous
//
#include <hip/hip_runtime.h>
#include <math.h>

#define BB 8
#define SS 1024
#define DD 512
#define HH 8
#define FFF 2048
// M rows total = BB*SS = 8192

typedef unsigned short ushortT;
typedef __attribute__((ext_vector_type(8))) short bf16x8;
typedef __attribute__((ext_vector_type(4))) float f32x4;

__device__ __forceinline__ float gelu_f(float x) {
    return 0.5f * x * (1.0f + erff(x * 0.70710678118654752f));
}

// round-to-nearest-even fp32 -> bf16 (finite inputs)
__device__ __forceinline__ ushortT f2bf(float f) {
    unsigned int u = __float_as_uint(f);
    return (ushortT)((u + 0x7fffu + ((u >> 16) & 1u)) >> 16);
}

__device__ __forceinline__ void gload_lds16(const void* g, void* l) {
    __builtin_amdgcn_global_load_lds(
        (const __attribute__((address_space(1))) void*)g,
        (__attribute__((address_space(3))) void*)l, 16, 0, 0);
}

// ---------------- fp32 -> bf16 cast (vectorized) ----------------
__global__ __launch_bounds__(256) void cast_bf16_kernel(const float* __restrict__ in,
                                                        ushortT* __restrict__ out) {
    int i = blockIdx.x * blockDim.x + threadIdx.x;   // per float4
    float4 v = ((const float4*)in)[i];
    ushort4 o;
    o.x = f2bf(v.x); o.y = f2bf(v.y); o.z = f2bf(v.z); o.w = f2bf(v.w);
    ((ushort4*)out)[i] = o;
}

// ---------------- tau embedding, bf16 out: T[bs,2f]=sin, [2f+1]=cos ----------------
__global__ __launch_bounds__(256) void tau_embed_kernel(const float* __restrict__ tau,
                                                        const float* __restrict__ freq,
                                                        ushortT* __restrict__ T) {
    int i = blockIdx.x * blockDim.x + threadIdx.x;   // 0 .. 8192*256-1
    int bs = i >> 8;
    int f  = i & 255;
    float v = tau[bs] * freq[f];
    float s, c;
    sincosf(v, &s, &c);
    ushort2 p;
    p.x = f2bf(s); p.y = f2bf(c);
    *(ushort2*)&T[(size_t)bs * DD + 2 * f] = p;
}

// ---------------- bf16 MFMA GEMM (m97 structure): C = act(A @ W^T + bias) [+res] ----
// A: [M,K] bf16 row-major, W: [N,K] bf16 row-major. Tile 128x128, BK=32, 4 waves.
// mode: 0 none, 1 tanh, 2 gelu. Cb!=null -> bf16 out, else fp32 to Cf.
__global__ __launch_bounds__(256) void gemm_bt_mfma(
        const ushortT* __restrict__ A, const ushortT* __restrict__ W,
        const float* __restrict__ bias, const float* __restrict__ res,
        float* __restrict__ Cf, ushortT* __restrict__ Cb,
        int M, int N, int K, int mode) {
    __shared__ ushortT As[128 * 32];    // 8 KB, row-major [128][32], 64 B rows
    __shared__ ushortT Bs[128 * 32];
    int t    = threadIdx.x;
    int lane = t & 63;
    int w    = t >> 6;                  // wave 0..3
    int wr   = w >> 1, wc = w & 1;      // 2x2 wave grid, 64x64 per wave
    int m0 = blockIdx.y << 7;
    int n0 = blockIdx.x << 7;

    f32x4 acc[4][4];
#pragma unroll
    for (int i = 0; i < 4; ++i)
#pragma unroll
        for (int j = 0; j < 4; ++j) acc[i][j] = (f32x4){0.f, 0.f, 0.f, 0.f};

    int srow = lane >> 2;
    int scol = (lane & 3) << 3;

    for (int k0 = 0; k0 < K; k0 += 32) {
#pragma unroll
        for (int i = 0; i < 2; ++i) {
            int off  = (i * 4 + w) << 10;
            int row  = (i * 64 + w * 16) + srow;
            gload_lds16(&A[(size_t)(m0 + row) * K + k0 + scol], (char*)As + off);
            gload_lds16(&W[(size_t)(n0 + row) * K + k0 + scol], (char*)Bs + off);
        }
        __syncthreads();

        bf16x8 af[4], bf[4];
#pragma unroll
        for (int i = 0; i < 4; ++i) {
            af[i] = *(const bf16x8*)&As[(wr * 64 + i * 16 + (lane & 15)) * 32 + ((lane >> 4) << 3)];
            bf[i] = *(const bf16x8*)&Bs[(wc * 64 + i * 16 + (lane & 15)) * 32 + ((lane >> 4) << 3)];
        }
#pragma unroll
        for (int mi = 0; mi < 4; ++mi)
#pragma unroll
            for (int ni = 0; ni < 4; ++ni)
                acc[mi][ni] = __builtin_amdgcn_mfma_f32_16x16x32_bf16(
                    af[mi], bf[ni], acc[mi][ni], 0, 0, 0);
        __syncthreads();
    }

    // epilogue: C/D layout row=(lane>>4)*4+reg, col=lane&15 [m89/m91]
    int cbase = n0 + wc * 64 + (lane & 15);
    float bcol[4];
#pragma unroll
    for (int ni = 0; ni < 4; ++ni) bcol[ni] = bias[cbase + ni * 16];
    int rbase = m0 + wr * 64 + ((lane >> 4) << 2);
#pragma unroll
    for (int mi = 0; mi < 4; ++mi) {
#pragma unroll
        for (int r = 0; r < 4; ++r) {
            size_t grow = (size_t)(rbase + mi * 16 + r);
#pragma unroll
            for (int ni = 0; ni < 4; ++ni) {
                int col = cbase + ni * 16;
                float v = acc[mi][ni][r] + bcol[ni];
                if (mode == 1)      v = tanhf(v);
                else if (mode == 2) v = gelu_f(v);
                if (res) v += res[grow * N + col];
                if (Cb)  Cb[grow * N + col] = f2bf(v);
                else     Cf[grow * N + col] = v;
            }
        }
    }
}

// ---------------- gating: out_bf16 = add + base*(1+g) ----------------
__global__ __launch_bounds__(256) void gate_combine_bf(
        const float* __restrict__ base, const float* __restrict__ g,
        const float* __restrict__ add, ushortT* __restrict__ outb) {
    int i = blockIdx.x * blockDim.x + threadIdx.x;   // per float4
    float4 bs = ((const float4*)base)[i];
    float4 gg = ((const float4*)g)[i];
    float4 ad = ((const float4*)add)[i];
    ushort4 o;
    o.x = f2bf(ad.x + bs.x * (1.f + gg.x));
    o.y = f2bf(ad.y + bs.y * (1.f + gg.y));
    o.z = f2bf(ad.z + bs.z * (1.f + gg.z));
    o.w = f2bf(ad.w + bs.w * (1.f + gg.w));
    ((ushort4*)outb)[i] = o;
}

// ---------------- bf16 MFMA flash attention with |dtau| bias ----------------
// Q,K,V bf16 [B,S,D], head h in cols h*64..h*64+63. O bf16, may alias Q
// (each block exclusively owns its 64-row x 64-col slice; Q consumed first).
__global__ __launch_bounds__(256) void attn_mfma(
        const ushortT* __restrict__ Q, const ushortT* __restrict__ K,
        const ushortT* __restrict__ V, const float* __restrict__ tau,
        const float* __restrict__ log_slopes, ushortT* __restrict__ O) {
    __shared__ ushortT Qs[2 * 64 * 32];   // [ks][row][32], 8 KB (m97 layout)
    __shared__ ushortT Ks[2 * 64 * 32];   // 8 KB
    __shared__ ushortT Vt[64 * 72];       // [d][72] transposed, +8 pad: 16B rows
    __shared__ ushortT Ps[64 * 72];       // [q][72] probs bf16, wave-private rows
    int t    = threadIdx.x;
    int lane = t & 63;
    int w    = t >> 6;
    int bh = blockIdx.y;
    int b  = bh >> 3, h = bh & 7;
    int q0 = blockIdx.x << 6;
    float slope = log1pf(expf(log_slopes[h]));   // softplus, GAMMA=1
    int lr = lane & 15;        // fragment row selector
    int hg = lane >> 4;        // k-group selector

    // ---- stage Q [2][64][32] (once) ----
#pragma unroll
    for (int ci = 0; ci < 2; ++ci) {
        int c = 2 * w + ci;
        int ks = c >> 2, row = ((c & 3) << 4) + (lane >> 2), ce = (lane & 3) << 3;
        gload_lds16(&Q[(size_t)(b * SS + q0 + row) * DD + (h << 6) + (ks << 5) + ce],
                    (char*)Qs + (c << 10) + lane * 16);
    }
    __syncthreads();
    bf16x8 aq[2];
#pragma unroll
    for (int ks = 0; ks < 2; ++ks)
        aq[ks] = *(const bf16x8*)&Qs[(ks << 11) + ((w << 4) + lr) * 32 + (hg << 3)];

    float tq[4];
#pragma unroll
    for (int r = 0; r < 4; ++r) tq[r] = tau[b * SS + q0 + (w << 4) + (hg << 2) + r];

    f32x4 acc_o[4];
    float m_run[4], l_run[4];
#pragma unroll
    for (int n = 0; n < 4; ++n) acc_o[n] = (f32x4){0.f, 0.f, 0.f, 0.f};
#pragma unroll
    for (int r = 0; r < 4; ++r) { m_run[r] = -INFINITY; l_run[r] = 0.f; }

    for (int kt = 0; kt < 16; ++kt) {
        int k0 = kt << 6;
        __syncthreads();   // prev tile's Ks/Vt reads done before overwrite
        // ---- stage K [2][64][32] ----
#pragma unroll
        for (int ci = 0; ci < 2; ++ci) {
            int c = 2 * w + ci;
            int ks = c >> 2, row = ((c & 3) << 4) + (lane >> 2), ce = (lane & 3) << 3;
            gload_lds16(&K[(size_t)(b * SS + k0 + row) * DD + (h << 6) + (ks << 5) + ce],
                        (char*)Ks + (c << 10) + lane * 16);
        }
        // ---- stage V transposed: Vt[d][k] ----
#pragma unroll
        for (int i = 0; i < 2; ++i) {
            int kk = (t >> 3) + (i << 5);        // key row 0..63
            int d0 = (t & 7) << 3;               // d block
            bf16x8 v8 = *(const bf16x8*)&V[(size_t)(b * SS + k0 + kk) * DD + (h << 6) + d0];
#pragma unroll
            for (int j = 0; j < 8; ++j) Vt[(d0 + j) * 72 + kk] = (ushortT)v8[j];
        }
        float tk[4];
#pragma unroll
        for (int n = 0; n < 4; ++n) tk[n] = tau[b * SS + k0 + (n << 4) + lr];
        __syncthreads();   // staging complete (drains vmcnt+lgkmcnt)

        // ---- QK^T: s[n][r] = S[q0+w*16+hg*4+r, k0+n*16+lr] ----
        f32x4 s[4];
#pragma unroll
        for (int n = 0; n < 4; ++n) {
            s[n] = (f32x4){0.f, 0.f, 0.f, 0.f};
            bf16x8 bk0 = *(const bf16x8*)&Ks[(0 << 11) + ((n << 4) + lr) * 32 + (hg << 3)];
            bf16x8 bk1 = *(const bf16x8*)&Ks[(1 << 11) + ((n << 4) + lr) * 32 + (hg << 3)];
            s[n] = __builtin_amdgcn_mfma_f32_16x16x32_bf16(aq[0], bk0, s[n], 0, 0, 0);
            s[n] = __builtin_amdgcn_mfma_f32_16x16x32_bf16(aq[1], bk1, s[n], 0, 0, 0);
        }

        // ---- bias + online softmax (rows wave-private) ----
        float p[4][4];   // [n][r]
        float fac[4];
#pragma unroll
        for (int r = 0; r < 4; ++r) {
            float lg[4];
#pragma unroll
            for (int n = 0; n < 4; ++n)
                lg[n] = s[n][r] * 0.125f - slope * fabsf(tq[r] - tk[n]);
            float mt = fmaxf(fmaxf(lg[0], lg[1]), fmaxf(lg[2], lg[3]));
            mt = fmaxf(mt, __shfl_xor(mt, 1));
            mt = fmaxf(mt, __shfl_xor(mt, 2));
            mt = fmaxf(mt, __shfl_xor(mt, 4));
            mt = fmaxf(mt, __shfl_xor(mt, 8));
            float mn = fmaxf(m_run[r], mt);
            fac[r] = expf(m_run[r] - mn);        // 0 on first tile (m_run=-inf)
            float rs = 0.f;
#pragma unroll
            for (int n = 0; n < 4; ++n) {
                p[n][r] = expf(lg[n] - mn);
                rs += p[n][r];
            }
            rs += __shfl_xor(rs, 1);
            rs += __shfl_xor(rs, 2);
            rs += __shfl_xor(rs, 4);
            rs += __shfl_xor(rs, 8);
            l_run[r] = l_run[r] * fac[r] + rs;
            m_run[r] = mn;
        }
#pragma unroll
        for (int n = 0; n < 4; ++n)
#pragma unroll
            for (int r = 0; r < 4; ++r) acc_o[n][r] *= fac[r];
        // write P (own wave's rows only -> no barrier needed before PV)
#pragma unroll
        for (int n = 0; n < 4; ++n)
#pragma unroll
            for (int r = 0; r < 4; ++r)
                Ps[((w << 4) + (hg << 2) + r) * 72 + (n << 4) + lr] = f2bf(p[n][r]);

        // ---- PV: acc_o[n][r] += P[q,:] x V[:, n*16+lr] ----
        bf16x8 ap0 = *(const bf16x8*)&Ps[((w << 4) + lr) * 72 + (hg << 3)];
        bf16x8 ap1 = *(const bf16x8*)&Ps[((w << 4) + lr) * 72 + 32 + (hg << 3)];
#pragma unroll
        for (int n = 0; n < 4; ++n) {
            bf16x8 bv0 = *(const bf16x8*)&Vt[((n << 4) + lr) * 72 + (hg << 3)];
            bf16x8 bv1 = *(const bf16x8*)&Vt[((n << 4) + lr) * 72 + 32 + (hg << 3)];
            acc_o[n] = __builtin_amdgcn_mfma_f32_16x16x32_bf16(ap0, bv0, acc_o[n], 0, 0, 0);
            acc_o[n] = __builtin_amdgcn_mfma_f32_16x16x32_bf16(ap1, bv1, acc_o[n], 0, 0, 0);
        }
    }

    // ---- epilogue: O = acc_o / l ----
    float inv[4];
#pragma unroll
    for (int r = 0; r < 4; ++r) inv[r] = 1.0f / l_run[r];
#pragma unroll
    for (int n = 0; n < 4; ++n)
#pragma unroll
        for (int r = 0; r < 4; ++r)
            O[(size_t)(b * SS + q0 + (w << 4) + (hg << 2) + r) * DD + (h << 6) + (n << 4) + lr]
                = f2bf(acc_o[n][r] * inv[r]);
}

// ---------------- layernorm over rows of 512 (fp32 out + optional bf16 out) --------
__global__ __launch_bounds__(64) void ln_kernel(const float* __restrict__ X,
                                                const float* __restrict__ g,
                                                const float* __restrict__ b,
                                                float* __restrict__ out,
                                                ushortT* __restrict__ outb) {
    int row = blockIdx.x;
    int t = threadIdx.x;
    const float* xr = X + (size_t)row * DD;
    float4 v0 = *(const float4*)&xr[t * 4];
    float4 v1 = *(const float4*)&xr[256 + t * 4];
    float s  = v0.x + v0.y + v0.z + v0.w + v1.x + v1.y + v1.z + v1.w;
    float sq = v0.x * v0.x + v0.y * v0.y + v0.z * v0.z + v0.w * v0.w
             + v1.x * v1.x + v1.y * v1.y + v1.z * v1.z + v1.w * v1.w;
#pragma unroll
    for (int off = 1; off < 64; off <<= 1) {
        s  += __shfl_xor(s, off);
        sq += __shfl_xor(sq, off);
    }
    float mean = s * (1.0f / 512.0f);
    float var  = sq * (1.0f / 512.0f) - mean * mean;
    float rstd = rsqrtf(var + 1e-5f);
    int c0 = t * 4, c1 = 256 + t * 4;
    float4 o0, o1;
    o0.x = (v0.x - mean) * rstd * g[c0 + 0] + b[c0 + 0];
    o0.y = (v0.y - mean) * rstd * g[c0 + 1] + b[c0 + 1];
    o0.z = (v0.z - mean) * rstd * g[c0 + 2] + b[c0 + 2];
    o0.w = (v0.w - mean) * rstd * g[c0 + 3] + b[c0 + 3];
    o1.x = (v1.x - mean) * rstd * g[c1 + 0] + b[c1 + 0];
    o1.y = (v1.y - mean) * rstd * g[c1 + 1] + b[c1 + 1];
    o1.z = (v1.z - mean) * rstd * g[c1 + 2] + b[c1 + 2];
    o1.w = (v1.w - mean) * rstd * g[c1 + 3] + b[c1 + 3];
    float* orow = out + (size_t)row * DD;
    *(float4*)&orow[c0] = o0;
    *(float4*)&orow[c1] = o1;
    if (outb) {
        ushort4 h0, h1;
        h0.x = f2bf(o0.x); h0.y = f2bf(o0.y); h0.z = f2bf(o0.z); h0.w = f2bf(o0.w);
        h1.x = f2bf(o1.x); h1.y = f2bf(o1.y); h1.z = f2bf(o1.z); h1.w = f2bf(o1.w);
        ushortT* brow = outb + (size_t)row * DD;
        *(ushort4*)&brow[c0] = h0;
        *(ushort4*)&brow[c1] = h1;
    }
}

extern "C" void kernel_launch(void* const* d_in, const int* in_sizes, int n_in,
                              void* d_out, int out_size, void* d_ws, size_t ws_size,
                              hipStream_t stream) {
    (void)in_sizes; (void)n_in; (void)out_size; (void)ws_size;
    const float* src        = (const float*)d_in[0];
    const float* tau        = (const float*)d_in[1];
    const float* Wq  = (const float*)d_in[2];  const float* bq  = (const float*)d_in[3];
    const float* Wk  = (const float*)d_in[4];  const float* bk  = (const float*)d_in[5];
    const float* Wv  = (const float*)d_in[6];  const float* bv  = (const float*)d_in[7];
    const float* Wo  = (const float*)d_in[8];  const float* bo  = (const float*)d_in[9];
    const float* Wqg = (const float*)d_in[10]; const float* bqg = (const float*)d_in[11];
    const float* Wqb = (const float*)d_in[12]; const float* bqb = (const float*)d_in[13];
    const float* Wkg = (const float*)d_in[14]; const float* bkg = (const float*)d_in[15];
    const float* Wkb = (const float*)d_in[16]; const float* bkb = (const float*)d_in[17];
    const float* log_slopes = (const float*)d_in[18];
    const float* W1  = (const float*)d_in[19]; const float* b1  = (const float*)d_in[20];
    const float* W2  = (const float*)d_in[21]; const float* b2  = (const float*)d_in[22];
    const float* ln1_g = (const float*)d_in[23]; const float* ln1_b = (const float*)d_in[24];
    const float* ln2_g = (const float*)d_in[25]; const float* ln2_b = (const float*)d_in[26];
    const float* tau_freq = (const float*)d_in[27];
    float* out = (float*)d_out;

    // Workspace (peak 88 MB, liveness-aliased):
    //  [ 0, 8)  T_bf (tau embed)  -> Vbf (after K-gate gemms)
    //  [ 8,16)  src_bf            -> X_bf (after V gemm)
    //  [16,24)  weights bf16 (8x0.5MB @16, W1 @20, W2 @22)
    //  [24,40)  f32 A: Q/K base   -> Xf (Wo out, LN1 in-place)
    //  [40,56)  f32 B: tanh gate  -> Yf (FFN2 out)
    //  [56,72)  f32 C: gate bias  -> H1 lo
    //  [72,80)  Qbf               -> Ctx_bf (attn in-place) ; later H1 mid
    //  [80,88)  Kbf               -> H1 hi
    char* ws = (char*)d_ws;
    const size_t MB = 1ull << 20;
    ushortT* T_bf   = (ushortT*)(ws + 0 * MB);
    ushortT* src_bf = (ushortT*)(ws + 8 * MB);
    ushortT* Wq_bf  = (ushortT*)(ws + 16 * MB);
    ushortT* Wk_bf  = (ushortT*)(ws + 16 * MB + 512 * 1024);
    ushortT* Wv_bf  = (ushortT*)(ws + 17 * MB);
    ushortT* Wo_bf  = (ushortT*)(ws + 17 * MB + 512 * 1024);
    ushortT* Wqg_bf = (ushortT*)(ws + 18 * MB);
    ushortT* Wqb_bf = (ushortT*)(ws + 18 * MB + 512 * 1024);
    ushortT* Wkg_bf = (ushortT*)(ws + 19 * MB);
    ushortT* Wkb_bf = (ushortT*)(ws + 19 * MB + 512 * 1024);
    ushortT* W1_bf  = (ushortT*)(ws + 20 * MB);
    ushortT* W2_bf  = (ushortT*)(ws + 22 * MB);
    float*   Af     = (float*)(ws + 24 * MB);   // base / Xf
    float*   Bf     = (float*)(ws + 40 * MB);   // gate / Yf
    float*   Cfb    = (float*)(ws + 56 * MB);   // bias / H1 lo
    ushortT* Qbf    = (ushortT*)(ws + 72 * MB); // -> Ctx_bf
    ushortT* Kbf    = (ushortT*)(ws + 80 * MB);
    ushortT* Vbf    = T_bf;                     // after T dead
    ushortT* Ctx_bf = Qbf;                      // attn in-place
    float*   Xf     = Af;
    ushortT* X_bf   = src_bf;
    ushortT* H1_bf  = (ushortT*)(ws + 56 * MB); // [56,88) = 32 MB
    float*   Yf     = Bf;

    const int M = BB * SS;                 // 8192
    dim3 blk(256);

    // --- casts (weights + src) ---
    cast_bf16_kernel<<<256,  blk, 0, stream>>>(Wq,  Wq_bf);
    cast_bf16_kernel<<<256,  blk, 0, stream>>>(Wk,  Wk_bf);
    cast_bf16_kernel<<<256,  blk, 0, stream>>>(Wv,  Wv_bf);
    cast_bf16_kernel<<<256,  blk, 0, stream>>>(Wo,  Wo_bf);
    cast_bf16_kernel<<<256,  blk, 0, stream>>>(Wqg, Wqg_bf);
    cast_bf16_kernel<<<256,  blk, 0, stream>>>(Wqb, Wqb_bf);
    cast_bf16_kernel<<<256,  blk, 0, stream>>>(Wkg, Wkg_bf);
    cast_bf16_kernel<<<256,  blk, 0, stream>>>(Wkb, Wkb_bf);
    cast_bf16_kernel<<<1024, blk, 0, stream>>>(W1,  W1_bf);
    cast_bf16_kernel<<<1024, blk, 0, stream>>>(W2,  W2_bf);
    cast_bf16_kernel<<<4096, blk, 0, stream>>>(src, src_bf);
    tau_embed_kernel<<<M, blk, 0, stream>>>(tau, tau_freq, T_bf);

    auto gemm = [&](const ushortT* A, const ushortT* Wb, const float* bias,
                    const float* res, float* Cf, ushortT* Cb, int N, int K, int mode) {
        dim3 g(N / 128, M / 128);
        gemm_bt_mfma<<<g, blk, 0, stream>>>(A, Wb, bias, res, Cf, Cb, M, N, K, mode);
    };

    // Q: base->Af, tanh-gate->Bf, bias->Cfb, combine -> Qbf (bf16)
    gemm(src_bf, Wq_bf,  bq,  nullptr, Af,  nullptr, DD, DD, 0);
    gemm(T_bf,   Wqg_bf, bqg, nullptr, Bf,  nullptr, DD, DD, 1);
    gemm(T_bf,   Wqb_bf, bqb, nullptr, Cfb, nullptr, DD, DD, 0);
    gate_combine_bf<<<(M * DD / 4) / 256, blk, 0, stream>>>(Af, Bf, Cfb, Qbf);
    // K -> Kbf (bf16)
    gemm(src_bf, Wk_bf,  bk,  nullptr, Af,  nullptr, DD, DD, 0);
    gemm(T_bf,   Wkg_bf, bkg, nullptr, Bf,  nullptr, DD, DD, 1);
    gemm(T_bf,   Wkb_bf, bkb, nullptr, Cfb, nullptr, DD, DD, 0);
    gate_combine_bf<<<(M * DD / 4) / 256, blk, 0, stream>>>(Af, Bf, Cfb, Kbf);
    // V -> Vbf (bf16 direct; T_bf dead now)
    gemm(src_bf, Wv_bf, bv, nullptr, nullptr, Vbf, DD, DD, 0);

    // attention (bf16 MFMA), O aliases Qbf
    attn_mfma<<<dim3(SS / 64, BB * HH), blk, 0, stream>>>(Qbf, Kbf, Vbf, tau, log_slopes, Ctx_bf);

    // X = Ctx@Wo^T + bo + src ; LN1 -> Xf (f32) + X_bf
    gemm(Ctx_bf, Wo_bf, bo, src, Xf, nullptr, DD, DD, 0);
    ln_kernel<<<M, 64, 0, stream>>>(Xf, ln1_g, ln1_b, Xf, X_bf);

    // FFN: H1 = gelu(X@W1^T+b1) bf16 ; Y = H1@W2^T + b2 + X
    gemm(X_bf, W1_bf, b1, nullptr, nullptr, H1_bf, FFF, DD, 2);
    gemm(H1_bf, W2_bf, b2, Xf, Yf, nullptr, DD, FFF, 0);

    // LN2 -> out
    ln_kernel<<<M, 64, 0, stream>>>(Yf, ln2_g, ln2_b, out, nullptr);
}